// Round 1
// baseline (121.179 us; speedup 1.0000x reference)
//
#include <hip/hip_runtime.h>

#define NB   2        // batches
#define GG   128      // grid extent
#define CC   128      // channels

// ---------------- kernel 1: per-batch min of coords (the "shift") ----------
__global__ void shift_kernel(const int* __restrict__ coords,
                             int* __restrict__ shift, int n) {
    __shared__ int smin[NB * 3];
    if (threadIdx.x < NB * 3) smin[threadIdx.x] = 0x7F7F7F7F;
    __syncthreads();
    for (int i = blockIdx.x * blockDim.x + threadIdx.x; i < n;
         i += gridDim.x * blockDim.x) {
        int b = coords[i * 4 + 0];
        atomicMin(&smin[b * 3 + 0], coords[i * 4 + 1]);
        atomicMin(&smin[b * 3 + 1], coords[i * 4 + 2]);
        atomicMin(&smin[b * 3 + 2], coords[i * 4 + 3]);
    }
    __syncthreads();
    if (threadIdx.x < NB * 3) atomicMin(&shift[threadIdx.x], smin[threadIdx.x]);
}

// ---------------- kernel 2: occupancy scatter (last-write-wins == max idx) --
__global__ void scatter_kernel(const int* __restrict__ coords,
                               const int* __restrict__ shift,
                               int* __restrict__ occ, int n) {
    int i = blockIdx.x * blockDim.x + threadIdx.x;
    if (i >= n) return;
    int b = coords[i * 4 + 0];
    int x = coords[i * 4 + 1] - shift[b * 3 + 0];
    int y = coords[i * 4 + 2] - shift[b * 3 + 1];
    int z = coords[i * 4 + 3] - shift[b * 3 + 2];
    size_t off = (((size_t)b * GG + x) * GG + y) * GG + z;
    atomicMax(&occ[off], i);
}

// ---------------- kernel 3: per-query trilinear gather ----------------------
// block = 128 threads (one per channel), grid = M blocks (one per query)
__global__ void __launch_bounds__(128)
query_kernel(const float* __restrict__ feats,
             const float* __restrict__ qpts,
             const int* __restrict__ shift,
             const int* __restrict__ occ,
             float* __restrict__ out_qf,
             float* __restrict__ out_idx,
             float* __restrict__ out_w,
             float* __restrict__ out_acc) {
    const int m   = blockIdx.x;
    const int tid = threadIdx.x;
    __shared__ int   s_idx[8];
    __shared__ float s_w[8];

    // broadcast load of the query point
    const float qbf = qpts[m * 4 + 0];
    const int   qb  = (int)qbf;
    const float q0  = qpts[m * 4 + 1] - (float)shift[qb * 3 + 0];
    const float q1  = qpts[m * 4 + 2] - (float)shift[qb * 3 + 1];
    const float q2  = qpts[m * 4 + 3] - (float)shift[qb * 3 + 2];

    if (tid < 8) {
        const int oi = (tid >> 2) & 1, oj = (tid >> 1) & 1, ok = tid & 1;
        const float b0 = floorf(q0), b1 = floorf(q1), b2 = floorf(q2);
        const float f0 = q0 - b0, f1 = q1 - b1, f2 = q2 - b2;
        const int c0 = (int)b0 + oi, c1 = (int)b1 + oj, c2 = (int)b2 + ok;
        const float w = (oi ? f0 : 1.0f - f0) *
                        (oj ? f1 : 1.0f - f1) *
                        (ok ? f2 : 1.0f - f2);
        const bool inb = (c0 >= 0) && (c0 < GG) && (c1 >= 0) && (c1 < GG) &&
                         (c2 >= 0) && (c2 < GG);
        int idx = -1;
        if (inb) idx = occ[(((size_t)qb * GG + c0) * GG + c1) * GG + c2];
        const bool  valid = inb && (idx != -1);
        const int   fidx  = valid ? idx : -1;
        const float fw    = valid ? w : 0.0f;
        s_idx[tid] = fidx;
        s_w[tid]   = fw;
        out_idx[(size_t)m * 8 + tid] = (float)fidx;
        out_w[(size_t)m * 8 + tid]   = fw;
        if (valid && fw != 0.0f) atomicAdd(&out_acc[fidx], fw);
    }
    __syncthreads();

    float acc = 0.0f;
#pragma unroll
    for (int k = 0; k < 8; ++k) {
        const int idx = s_idx[k];
        if (idx >= 0) acc += s_w[k] * feats[(size_t)idx * CC + tid];
    }
    out_qf[(size_t)m * CC + tid] = acc;
}

extern "C" void kernel_launch(void* const* d_in, const int* in_sizes, int n_in,
                              void* d_out, int out_size, void* d_ws, size_t ws_size,
                              hipStream_t stream) {
    const float* feats  = (const float*)d_in[0];
    const int*   coords = (const int*)d_in[1];
    const float* qpts   = (const float*)d_in[2];

    const int n  = in_sizes[1] / 4;  // N points
    const int mq = in_sizes[2] / 4;  // M queries

    float* out     = (float*)d_out;
    float* out_qf  = out;
    float* out_idx = out_qf  + (size_t)mq * CC;
    float* out_w   = out_idx + (size_t)mq * 8;
    float* out_acc = out_w   + (size_t)mq * 8;

    int* shift = (int*)d_ws;
    int* occ   = (int*)((char*)d_ws + 256);
    const size_t occ_bytes = (size_t)NB * GG * GG * GG * sizeof(int);

    // inits (graph-capture-safe async memsets)
    hipMemsetAsync(shift, 0x7F, NB * 3 * sizeof(int), stream);   // big positive ints
    hipMemsetAsync(occ, 0xFF, occ_bytes, stream);                // -1 everywhere
    hipMemsetAsync(out_acc, 0, (size_t)n * sizeof(float), stream);

    const int blk = 256;
    shift_kernel  <<<(n + blk - 1) / blk, blk, 0, stream>>>(coords, shift, n);
    scatter_kernel<<<(n + blk - 1) / blk, blk, 0, stream>>>(coords, shift, occ, n);
    query_kernel  <<<mq, CC, 0, stream>>>(feats, qpts, shift, occ,
                                          out_qf, out_idx, out_w, out_acc);
}

// Round 2
// 78.518 us; speedup vs baseline: 1.5433x; 1.5433x over previous
//
#include <hip/hip_runtime.h>

#define NB   2        // batches
#define GG   128      // grid extent
#define CC   128      // channels
#define QPB  8        // queries per block
#define BLK  256      // threads per block

// ---------------- kernel 1: per-batch min of coords (the "shift") ----------
__global__ void shift_kernel(const int* __restrict__ coords,
                             int* __restrict__ shift, int n) {
    __shared__ int smin[NB * 3];
    if (threadIdx.x < NB * 3) smin[threadIdx.x] = 0x7F7F7F7F;
    __syncthreads();
    for (int i = blockIdx.x * blockDim.x + threadIdx.x; i < n;
         i += gridDim.x * blockDim.x) {
        int b = coords[i * 4 + 0];
        atomicMin(&smin[b * 3 + 0], coords[i * 4 + 1]);
        atomicMin(&smin[b * 3 + 1], coords[i * 4 + 2]);
        atomicMin(&smin[b * 3 + 2], coords[i * 4 + 3]);
    }
    __syncthreads();
    if (threadIdx.x < NB * 3) atomicMin(&shift[threadIdx.x], smin[threadIdx.x]);
}

// ---------------- kernel 2: occupancy scatter (last-write-wins == max idx) --
__global__ void scatter_kernel(const int* __restrict__ coords,
                               const int* __restrict__ shift,
                               int* __restrict__ occ, int n) {
    int i = blockIdx.x * blockDim.x + threadIdx.x;
    if (i >= n) return;
    int b = coords[i * 4 + 0];
    int x = coords[i * 4 + 1] - shift[b * 3 + 0];
    int y = coords[i * 4 + 2] - shift[b * 3 + 1];
    int z = coords[i * 4 + 3] - shift[b * 3 + 2];
    size_t off = (((size_t)b * GG + x) * GG + y) * GG + z;
    atomicMax(&occ[off], i);
}

// ---------------- kernel 3: trilinear gather, 8 queries per block -----------
// phase 1: wave 0's 64 lanes = 8 queries x 8 corners, independent occ loads
// phase 2: 256 threads = 8 queries x 32 lanes, float4 channel gather
__global__ void __launch_bounds__(BLK)
query_kernel(const float* __restrict__ feats,
             const float* __restrict__ qpts,
             const int* __restrict__ shift,
             const int* __restrict__ occ,
             float* __restrict__ out_qf,
             float* __restrict__ out_idx,
             float* __restrict__ out_w,
             float* __restrict__ out_acc, int mq) {
    const int tid   = threadIdx.x;
    const int qbase = blockIdx.x * QPB;
    __shared__ int   s_idx[QPB][8];
    __shared__ float s_w[QPB][8];

    if (tid < QPB * 8) {                       // one wave: 64 corner tasks
        const int q  = tid >> 3;               // 0..7 query in block
        const int cn = tid & 7;                // 0..7 corner
        const int gq = qbase + q;
        int   fidx = -1;
        float fw   = 0.0f;
        if (gq < mq) {
            const int   qb = (int)qpts[(size_t)gq * 4 + 0];
            const float q0 = qpts[(size_t)gq * 4 + 1] - (float)shift[qb * 3 + 0];
            const float q1 = qpts[(size_t)gq * 4 + 2] - (float)shift[qb * 3 + 1];
            const float q2 = qpts[(size_t)gq * 4 + 3] - (float)shift[qb * 3 + 2];
            const int oi = (cn >> 2) & 1, oj = (cn >> 1) & 1, ok = cn & 1;
            const float b0 = floorf(q0), b1 = floorf(q1), b2 = floorf(q2);
            const float f0 = q0 - b0, f1 = q1 - b1, f2 = q2 - b2;
            const int c0 = (int)b0 + oi, c1 = (int)b1 + oj, c2 = (int)b2 + ok;
            const float w = (oi ? f0 : 1.0f - f0) *
                            (oj ? f1 : 1.0f - f1) *
                            (ok ? f2 : 1.0f - f2);
            const bool inb = (c0 >= 0) && (c0 < GG) && (c1 >= 0) && (c1 < GG) &&
                             (c2 >= 0) && (c2 < GG);
            int idx = -1;
            if (inb) idx = occ[(((size_t)qb * GG + c0) * GG + c1) * GG + c2];
            const bool valid = inb && (idx != -1);
            fidx = valid ? idx : -1;
            fw   = valid ? w : 0.0f;
            out_idx[(size_t)gq * 8 + cn] = (float)fidx;
            out_w[(size_t)gq * 8 + cn]   = fw;
            if (fidx >= 0 && fw != 0.0f) atomicAdd(&out_acc[fidx], fw);
        }
        s_idx[q][cn] = fidx;
        s_w[q][cn]   = fw;
    }
    __syncthreads();

    const int q  = tid >> 5;                   // 0..7 query in block
    const int c4 = (tid & 31) << 2;            // channel*4
    const int gq = qbase + q;
    if (gq >= mq) return;
    float4 acc = make_float4(0.0f, 0.0f, 0.0f, 0.0f);
#pragma unroll
    for (int k = 0; k < 8; ++k) {
        const int idx = s_idx[q][k];
        if (idx >= 0) {
            const float  w = s_w[q][k];
            const float4 f = *(const float4*)&feats[(size_t)idx * CC + c4];
            acc.x += w * f.x; acc.y += w * f.y;
            acc.z += w * f.z; acc.w += w * f.w;
        }
    }
    *(float4*)&out_qf[(size_t)gq * CC + c4] = acc;
}

extern "C" void kernel_launch(void* const* d_in, const int* in_sizes, int n_in,
                              void* d_out, int out_size, void* d_ws, size_t ws_size,
                              hipStream_t stream) {
    const float* feats  = (const float*)d_in[0];
    const int*   coords = (const int*)d_in[1];
    const float* qpts   = (const float*)d_in[2];

    const int n  = in_sizes[1] / 4;  // N points
    const int mq = in_sizes[2] / 4;  // M queries

    float* out     = (float*)d_out;
    float* out_qf  = out;
    float* out_idx = out_qf  + (size_t)mq * CC;
    float* out_w   = out_idx + (size_t)mq * 8;
    float* out_acc = out_w   + (size_t)mq * 8;

    int* shift = (int*)d_ws;
    int* occ   = (int*)((char*)d_ws + 256);
    const size_t occ_bytes = (size_t)NB * GG * GG * GG * sizeof(int);

    hipMemsetAsync(shift, 0x7F, NB * 3 * sizeof(int), stream);
    hipMemsetAsync(occ, 0xFF, occ_bytes, stream);
    hipMemsetAsync(out_acc, 0, (size_t)n * sizeof(float), stream);

    const int blk = 256;
    shift_kernel  <<<(n + blk - 1) / blk, blk, 0, stream>>>(coords, shift, n);
    scatter_kernel<<<(n + blk - 1) / blk, blk, 0, stream>>>(coords, shift, occ, n);
    const int qblocks = (mq + QPB - 1) / QPB;
    query_kernel  <<<qblocks, BLK, 0, stream>>>(feats, qpts, shift, occ,
                                                out_qf, out_idx, out_w, out_acc, mq);
}

// Round 3
// 70.320 us; speedup vs baseline: 1.7233x; 1.1166x over previous
//
#include <hip/hip_runtime.h>

#define NB   2        // batches
#define GG   128      // grid extent
#define CC   128      // channels

typedef float v4f __attribute__((ext_vector_type(4)));

constexpr int OCC_INTS = NB * GG * GG * GG;   // 4,194,304 ints = 16 MiB

// ---- K0: init occ = -1, out_acc = 0, shift = INT_MAX (no rocclr fills) ----
__global__ void __launch_bounds__(256)
init_kernel(int* __restrict__ occ, float* __restrict__ acc,
            int* __restrict__ shift, int n) {
    const int tid = blockIdx.x * blockDim.x + threadIdx.x;
    const int nth = gridDim.x * blockDim.x;
    if (blockIdx.x == 0 && threadIdx.x < NB * 3) shift[threadIdx.x] = 0x7FFFFFFF;
    int4* occ4 = (int4*)occ;
    const int no4 = OCC_INTS / 4;
    for (int i = tid; i < no4; i += nth) occ4[i] = make_int4(-1, -1, -1, -1);
    for (int i = tid; i < n; i += nth) acc[i] = 0.0f;
}

// ---- K1: per-batch min of coords --------------------------------------------
__global__ void shift_kernel(const int* __restrict__ coords,
                             int* __restrict__ shift, int n) {
    __shared__ int smin[NB * 3];
    if (threadIdx.x < NB * 3) smin[threadIdx.x] = 0x7FFFFFFF;
    __syncthreads();
    for (int i = blockIdx.x * blockDim.x + threadIdx.x; i < n;
         i += gridDim.x * blockDim.x) {
        int b = coords[i * 4 + 0];
        atomicMin(&smin[b * 3 + 0], coords[i * 4 + 1]);
        atomicMin(&smin[b * 3 + 1], coords[i * 4 + 2]);
        atomicMin(&smin[b * 3 + 2], coords[i * 4 + 3]);
    }
    __syncthreads();
    if (threadIdx.x < NB * 3) atomicMin(&shift[threadIdx.x], smin[threadIdx.x]);
}

// ---- K2: occupancy scatter (last-write-wins == max idx) ---------------------
__global__ void scatter_kernel(const int* __restrict__ coords,
                               const int* __restrict__ shift,
                               int* __restrict__ occ, int n) {
    int i = blockIdx.x * blockDim.x + threadIdx.x;
    if (i >= n) return;
    int b = coords[i * 4 + 0];
    int x = coords[i * 4 + 1] - shift[b * 3 + 0];
    int y = coords[i * 4 + 2] - shift[b * 3 + 1];
    int z = coords[i * 4 + 3] - shift[b * 3 + 2];
    size_t off = (((size_t)b * GG + x) * GG + y) * GG + z;
    atomicMax(&occ[off], i);
}

// ---- K3: corner kernel — one thread per (query, corner) ---------------------
__global__ void __launch_bounds__(256)
corner_kernel(const float* __restrict__ qpts,
              const int* __restrict__ shift,
              const int* __restrict__ occ,
              float* __restrict__ out_idx,
              float* __restrict__ out_w,
              float* __restrict__ out_acc, int mq) {
    const int t = blockIdx.x * 256 + threadIdx.x;
    if (t >= mq * 8) return;
    const int gq = t >> 3;
    const int cn = t & 7;

    const float4 qp = ((const float4*)qpts)[gq];
    const int   qb = (int)qp.x;
    const float q0 = qp.y - (float)shift[qb * 3 + 0];
    const float q1 = qp.z - (float)shift[qb * 3 + 1];
    const float q2 = qp.w - (float)shift[qb * 3 + 2];

    const int oi = (cn >> 2) & 1, oj = (cn >> 1) & 1, ok = cn & 1;
    const float b0 = floorf(q0), b1 = floorf(q1), b2 = floorf(q2);
    const float f0 = q0 - b0, f1 = q1 - b1, f2 = q2 - b2;
    const int c0 = (int)b0 + oi, c1 = (int)b1 + oj, c2 = (int)b2 + ok;
    const float w = (oi ? f0 : 1.0f - f0) *
                    (oj ? f1 : 1.0f - f1) *
                    (ok ? f2 : 1.0f - f2);
    const bool inb = (c0 >= 0) && (c0 < GG) && (c1 >= 0) && (c1 < GG) &&
                     (c2 >= 0) && (c2 < GG);
    int idx = -1;
    if (inb) idx = occ[(((size_t)qb * GG + c0) * GG + c1) * GG + c2];
    const bool  valid = inb && (idx != -1);
    const int   fidx  = valid ? idx : -1;
    const float fw    = valid ? w : 0.0f;

    out_idx[t] = (float)fidx;      // idx < 2^24 -> exact in float
    out_w[t]   = fw;
    if (fidx >= 0 && fw != 0.0f) atomicAdd(&out_acc[fidx], fw);
}

// ---- K4: gather kernel — 32 lanes per query, float4 channels ----------------
__global__ void __launch_bounds__(256)
gather_kernel(const float* __restrict__ feats,
              const float* __restrict__ out_idx,
              const float* __restrict__ out_w,
              float* __restrict__ out_qf, int mq) {
    const int t  = blockIdx.x * 256 + threadIdx.x;
    const int gq = t >> 5;
    if (gq >= mq) return;
    const int c4 = (threadIdx.x & 31) << 2;     // channel*4
    const int k0 = threadIdx.x & 7;             // my corner slot

    int   my_idx = (int)out_idx[(size_t)gq * 8 + k0];
    float my_w   = out_w[(size_t)gq * 8 + k0];

    v4f acc = {0.0f, 0.0f, 0.0f, 0.0f};
#pragma unroll
    for (int k = 0; k < 8; ++k) {
        const int   idx = __shfl(my_idx, k, 8);
        const float w   = __shfl(my_w, k, 8);
        if (idx >= 0) {
            const v4f f = *(const v4f*)&feats[(size_t)idx * CC + c4];
            acc += w * f;
        }
    }
    __builtin_nontemporal_store(acc, (v4f*)&out_qf[(size_t)gq * CC + c4]);
}

extern "C" void kernel_launch(void* const* d_in, const int* in_sizes, int n_in,
                              void* d_out, int out_size, void* d_ws, size_t ws_size,
                              hipStream_t stream) {
    const float* feats  = (const float*)d_in[0];
    const int*   coords = (const int*)d_in[1];
    const float* qpts   = (const float*)d_in[2];

    const int n  = in_sizes[1] / 4;  // N points
    const int mq = in_sizes[2] / 4;  // M queries

    float* out     = (float*)d_out;
    float* out_qf  = out;
    float* out_idx = out_qf  + (size_t)mq * CC;
    float* out_w   = out_idx + (size_t)mq * 8;
    float* out_acc = out_w   + (size_t)mq * 8;

    int* shift = (int*)d_ws;
    int* occ   = (int*)((char*)d_ws + 256);

    const int blk = 256;
    init_kernel   <<<2048, blk, 0, stream>>>(occ, out_acc, shift, n);
    shift_kernel  <<<(n + blk - 1) / blk, blk, 0, stream>>>(coords, shift, n);
    scatter_kernel<<<(n + blk - 1) / blk, blk, 0, stream>>>(coords, shift, occ, n);
    corner_kernel <<<(mq * 8 + blk - 1) / blk, blk, 0, stream>>>(
        qpts, shift, occ, out_idx, out_w, out_acc, mq);
    gather_kernel <<<((mq * 32) + blk - 1) / blk, blk, 0, stream>>>(
        feats, out_idx, out_w, out_qf, mq);
}

// Round 4
// 66.479 us; speedup vs baseline: 1.8228x; 1.0578x over previous
//
#include <hip/hip_runtime.h>

#define NB   2        // batches
#define GG   128      // grid extent
#define CC   128      // channels
#define QPB  64       // queries per block in fused query kernel

typedef float v4f __attribute__((ext_vector_type(4)));

constexpr int OCC_INTS = NB * GG * GG * GG;   // 16 MiB

// ---- K0: init occ = -1, out_acc = 0, shift = INT_MAX ------------------------
__global__ void __launch_bounds__(256)
init_kernel(int* __restrict__ occ, float* __restrict__ acc,
            int* __restrict__ shift, int n) {
    const int tid = blockIdx.x * 256 + threadIdx.x;
    const int nth = gridDim.x * 256;
    if (tid < NB * 3) shift[tid] = 0x7FFFFFFF;
    int4* occ4 = (int4*)occ;
    for (int i = tid; i < OCC_INTS / 4; i += nth)
        occ4[i] = make_int4(-1, -1, -1, -1);
    for (int i = tid; i < n; i += nth) acc[i] = 0.0f;
}

// ---- K1: fused shift-min + UNSHIFTED occupancy scatter ----------------------
// scatter is translation-invariant: occ_u[c] = occ_ref[c - shift]; queries add
// shift back to the address. So scatter needs no shift -> one coords pass.
__global__ void __launch_bounds__(256)
scatter_kernel(const int4* __restrict__ coords, int* __restrict__ shift,
               int* __restrict__ occ, int n) {
    __shared__ int smin[NB * 3];
    if (threadIdx.x < NB * 3) smin[threadIdx.x] = 0x7FFFFFFF;
    __syncthreads();
    for (int i = blockIdx.x * 256 + threadIdx.x; i < n; i += gridDim.x * 256) {
        const int4 c = coords[i];                  // (b, x, y, z)
        atomicMin(&smin[c.x * 3 + 0], c.y);
        atomicMin(&smin[c.x * 3 + 1], c.z);
        atomicMin(&smin[c.x * 3 + 2], c.w);
        atomicMax(&occ[((c.x * GG + c.y) * GG + c.z) * GG + c.w], i);
    }
    __syncthreads();
    if (threadIdx.x < NB * 3) atomicMin(&shift[threadIdx.x], smin[threadIdx.x]);
}

// ---- K2: fused corner + gather ---------------------------------------------
// phase 1: wave 0, one thread per query: 8-deep independent occ loads
// phase 2: 8 passes of (8 queries x 32 lanes), float4 feature gather via LDS
__global__ void __launch_bounds__(256)
query_kernel(const float* __restrict__ feats,
             const v4f* __restrict__ qpts,
             const int* __restrict__ shift,
             const int* __restrict__ occ,
             float* __restrict__ out_qf,
             float* __restrict__ out_idx,
             float* __restrict__ out_w,
             float* __restrict__ out_acc, int mq) {
    __shared__ int   s_idx[QPB][8];
    __shared__ float s_w[QPB][8];
    const int tid   = threadIdx.x;
    const int qbase = blockIdx.x * QPB;

    if (tid < QPB) {
        const int gq = qbase + tid;
        int   lidx[8];
        float lw[8];
#pragma unroll
        for (int cn = 0; cn < 8; ++cn) { lidx[cn] = -1; lw[cn] = 0.0f; }
        if (gq < mq) {
            const v4f qp = qpts[gq];
            const int qb = (int)qp.x;
            const int s0 = shift[qb * 3 + 0], s1 = shift[qb * 3 + 1],
                      s2 = shift[qb * 3 + 2];
            // reproduce reference arithmetic exactly (shifted space)
            const float q0 = qp.y - (float)s0, q1 = qp.z - (float)s1,
                        q2 = qp.w - (float)s2;
            const float b0 = floorf(q0), b1 = floorf(q1), b2 = floorf(q2);
            const float f0 = q0 - b0, f1 = q1 - b1, f2 = q2 - b2;
            const int i0 = (int)b0, i1 = (int)b1, i2 = (int)b2;
            const int u0 = i0 + s0, u1 = i1 + s1, u2 = i2 + s2;  // unshifted base
#pragma unroll
            for (int cn = 0; cn < 8; ++cn) {
                const int oi = (cn >> 2) & 1, oj = (cn >> 1) & 1, ok = cn & 1;
                const int c0 = i0 + oi, c1 = i1 + oj, c2 = i2 + ok; // ref space
                const int a0 = u0 + oi, a1 = u1 + oj, a2 = u2 + ok; // occ addr
                const float w = (oi ? f0 : 1.0f - f0) *
                                (oj ? f1 : 1.0f - f1) *
                                (ok ? f2 : 1.0f - f2);
                const bool inb = c0 >= 0 && c0 < GG && c1 >= 0 && c1 < GG &&
                                 c2 >= 0 && c2 < GG &&
                                 a0 < GG && a1 < GG && a2 < GG;
                int idx = -1;
                if (inb) idx = occ[((qb * GG + a0) * GG + a1) * GG + a2];
                const float fw = (idx != -1) ? w : 0.0f;
                lidx[cn] = idx;
                lw[cn]   = fw;
                if (idx >= 0 && fw != 0.0f) atomicAdd(&out_acc[idx], fw);
            }
            const v4f vi0 = {(float)lidx[0], (float)lidx[1], (float)lidx[2], (float)lidx[3]};
            const v4f vi1 = {(float)lidx[4], (float)lidx[5], (float)lidx[6], (float)lidx[7]};
            const v4f vw0 = {lw[0], lw[1], lw[2], lw[3]};
            const v4f vw1 = {lw[4], lw[5], lw[6], lw[7]};
            __builtin_nontemporal_store(vi0, (v4f*)&out_idx[(size_t)gq * 8]);
            __builtin_nontemporal_store(vi1, (v4f*)&out_idx[(size_t)gq * 8 + 4]);
            __builtin_nontemporal_store(vw0, (v4f*)&out_w[(size_t)gq * 8]);
            __builtin_nontemporal_store(vw1, (v4f*)&out_w[(size_t)gq * 8 + 4]);
        }
#pragma unroll
        for (int cn = 0; cn < 8; ++cn) {
            s_idx[tid][cn] = lidx[cn];
            s_w[tid][cn]   = lw[cn];
        }
    }
    __syncthreads();

    const int lane = tid & 31;
    const int qsub = tid >> 5;        // 0..7
    const int c4   = lane << 2;       // channel*4
#pragma unroll
    for (int p = 0; p < 8; ++p) {
        const int q  = p * 8 + qsub;  // 0..63
        const int gq = qbase + q;
        if (gq >= mq) continue;
        v4f acc = {0.0f, 0.0f, 0.0f, 0.0f};
#pragma unroll
        for (int k = 0; k < 8; ++k) {
            const int idx = s_idx[q][k];
            if (idx >= 0) {
                const float w = s_w[q][k];
                const v4f f = *(const v4f*)&feats[(size_t)idx * CC + c4];
                acc += w * f;
            }
        }
        __builtin_nontemporal_store(acc, (v4f*)&out_qf[(size_t)gq * CC + c4]);
    }
}

extern "C" void kernel_launch(void* const* d_in, const int* in_sizes, int n_in,
                              void* d_out, int out_size, void* d_ws, size_t ws_size,
                              hipStream_t stream) {
    const float* feats  = (const float*)d_in[0];
    const int4*  coords = (const int4*)d_in[1];
    const v4f*   qpts   = (const v4f*)d_in[2];

    const int n  = in_sizes[1] / 4;  // N points
    const int mq = in_sizes[2] / 4;  // M queries

    float* out     = (float*)d_out;
    float* out_qf  = out;
    float* out_idx = out_qf  + (size_t)mq * CC;
    float* out_w   = out_idx + (size_t)mq * 8;
    float* out_acc = out_w   + (size_t)mq * 8;

    int* shift = (int*)d_ws;
    int* occ   = (int*)((char*)d_ws + 256);

    init_kernel   <<<2048, 256, 0, stream>>>(occ, out_acc, shift, n);
    scatter_kernel<<<(n + 255) / 256, 256, 0, stream>>>(coords, shift, occ, n);
    query_kernel  <<<(mq + QPB - 1) / QPB, 256, 0, stream>>>(
        feats, qpts, shift, occ, out_qf, out_idx, out_w, out_acc, mq);
}